// Round 1
// baseline (197.479 us; speedup 1.0000x reference)
//
#include <hip/hip_runtime.h>

#define NN 4096
#define DIN 512
#define DOUT 128
#define NH 4
#define LOG2E 1.44269504088896340736f

typedef __bf16 bf16x8 __attribute__((ext_vector_type(8)));
typedef float f32x4 __attribute__((ext_vector_type(4)));
typedef unsigned short u16;
typedef u16 u16x8 __attribute__((ext_vector_type(8)));

static __device__ __forceinline__ u16 f2bf(float f) {
  __bf16 h = (__bf16)f;
  return __builtin_bit_cast(u16, h);
}

// Kernel A: h = x@W in fp32; outputs hT (bf16, [DOUT][NN]), el ([NN][NH], *log2e),
// erT ([NH][NN], *log2e).
__global__ __launch_bounds__(512, 1) void precompute_kernel(
    const float* __restrict__ x, const float* __restrict__ W,
    const float* __restrict__ alw, const float* __restrict__ arw,
    u16* __restrict__ hT, float* __restrict__ el, float* __restrict__ erT)
{
  __shared__ __align__(16) float W_lds[128 * 128];
  __shared__ __align__(16) float x_lds[16 * 128];
  const int t = threadIdx.x;
  const int i0 = blockIdx.x * 16;
  const int r = t >> 5;        // row 0..15
  const int c = t & 31;        // col group
  const int d0 = c * 4;        // 4 output cols per thread
  float a0 = 0.f, a1 = 0.f, a2 = 0.f, a3 = 0.f;
  for (int kc = 0; kc < 4; ++kc) {
    __syncthreads();
    const float4* Wg4 = (const float4*)(W + kc * (128 * 128));
    float4* Wl4 = (float4*)W_lds;
    #pragma unroll
    for (int q = 0; q < 8; ++q) Wl4[t + q * 512] = Wg4[t + q * 512];
    ((float4*)x_lds)[t] =
        *(const float4*)(x + (size_t)(i0 + r) * DIN + kc * 128 + c * 4);
    __syncthreads();
    #pragma unroll 8
    for (int k = 0; k < 128; ++k) {
      const float xv = x_lds[r * 128 + k];
      const float4 w4 = ((const float4*)W_lds)[k * 32 + c];
      a0 += xv * w4.x; a1 += xv * w4.y; a2 += xv * w4.z; a3 += xv * w4.w;
    }
  }
  const int i = i0 + r;
  // transposed bf16 store (scatter; L2 merges — hT is only 1 MB)
  hT[(size_t)(d0 + 0) * NN + i] = f2bf(a0);
  hT[(size_t)(d0 + 1) * NN + i] = f2bf(a1);
  hT[(size_t)(d0 + 2) * NN + i] = f2bf(a2);
  hT[(size_t)(d0 + 3) * NN + i] = f2bf(a3);
  // el/er partials over this thread's 4 d-columns
  float elp[NH], erp[NH];
  #pragma unroll
  for (int hh = 0; hh < NH; ++hh) {
    const float* alr = alw + hh * DOUT + d0;
    const float* arr = arw + hh * DOUT + d0;
    elp[hh] = a0 * alr[0] + a1 * alr[1] + a2 * alr[2] + a3 * alr[3];
    erp[hh] = a0 * arr[0] + a1 * arr[1] + a2 * arr[2] + a3 * arr[3];
  }
  // reduce across the 32 lanes sharing a row (lanes r*32..r*32+31 of the wave)
  #pragma unroll
  for (int hh = 0; hh < NH; ++hh) {
    #pragma unroll
    for (int off = 1; off < 32; off <<= 1) {
      elp[hh] += __shfl_xor(elp[hh], off);
      erp[hh] += __shfl_xor(erp[hh], off);
    }
  }
  if (c == 0) {
    *(float4*)(el + (size_t)i * NH) =
        make_float4(elp[0] * LOG2E, elp[1] * LOG2E, elp[2] * LOG2E, elp[3] * LOG2E);
    #pragma unroll
    for (int hh = 0; hh < NH; ++hh) erT[(size_t)hh * NN + i] = erp[hh] * LOG2E;
  }
}

// Kernel B: fused weight-gen + mask + row-sum + PV GEMM + normalize + bias.
// Block: 16 graph rows x 4 heads = 64 MFMA rows (m' = head*16 + il), 128 cols.
__global__ __launch_bounds__(512, 1) void gat_main(
    const float* __restrict__ adj, const u16* __restrict__ hT,
    const float* __restrict__ el, const float* __restrict__ erT,
    const float* __restrict__ bias, float* __restrict__ out)
{
  __shared__ __align__(16) u16 A_lds[64 * 64];    // weight tile, XOR-swizzled
  __shared__ __align__(16) u16 B_lds[128 * 64];   // hT tile [d][k], XOR-swizzled
  __shared__ float S_lds[64];
  char* Ab = (char*)A_lds;
  char* Bb = (char*)B_lds;
  const int t = threadIdx.x;
  const int i0 = blockIdx.x * 16;
  // ---- A'-generation mapping: thread -> (m' row, 8 consecutive j) ----
  const int row = t >> 3;              // m' in 0..63
  const int head = row >> 4;
  const int il = row & 15;
  const int j0 = (t & 7) * 8;
  const float elv = el[(size_t)(i0 + il) * NH + head];   // pre-scaled by log2e
  const float* adjrow = adj + (size_t)(i0 + il) * NN;
  const float* errow = erT + (size_t)head * NN;
  const unsigned a_waddr = (unsigned)(row * 128 + j0 * 2) ^ (unsigned)((row & 7) << 4);
  // ---- B staging mapping: 2 chunks of 8 bf16 per thread ----
  const int bd = t >> 3;               // d row 0..63 (chunk2: +64)
  const int bk0 = (t & 7) * 8;
  const unsigned b_waddr0 = (unsigned)(bd * 128 + bk0 * 2) ^ (unsigned)((bd & 7) << 4);
  const unsigned b_waddr1 = (unsigned)((bd + 64) * 128 + bk0 * 2) ^ (unsigned)((bd & 7) << 4);
  // ---- MFMA mapping: wave w -> row-tile rt=w>>1 (== head), col-half ch=w&1 ----
  const int lane = t & 63;
  const int w = t >> 6;
  const int rt = w >> 1;
  const int ch = w & 1;
  const int l15 = lane & 15;
  const int lhi = lane >> 4;
  const int am = rt * 16 + l15;
  const unsigned aswz = (unsigned)((am & 7) << 4);
  f32x4 acc[4];
  #pragma unroll
  for (int ct = 0; ct < 4; ++ct) acc[ct] = (f32x4){0.f, 0.f, 0.f, 0.f};
  float Sp = 0.f;

  for (int jt = 0; jt < 64; ++jt) {
    const int jb = jt * 64;
    __syncthreads();   // previous iteration's MFMA reads done
    // ---- generate A' tile ----
    const float4 ad0 = *(const float4*)(adjrow + jb + j0);
    const float4 ad1 = *(const float4*)(adjrow + jb + j0 + 4);
    const float4 er0 = *(const float4*)(errow + jb + j0);
    const float4 er1 = *(const float4*)(errow + jb + j0 + 4);
    float av[8];
    {
      float e;
      e = elv + er0.x; av[0] = ad0.x * exp2f(fmaxf(e, 0.f) + 0.2f * fminf(e, 0.f));
      e = elv + er0.y; av[1] = ad0.y * exp2f(fmaxf(e, 0.f) + 0.2f * fminf(e, 0.f));
      e = elv + er0.z; av[2] = ad0.z * exp2f(fmaxf(e, 0.f) + 0.2f * fminf(e, 0.f));
      e = elv + er0.w; av[3] = ad0.w * exp2f(fmaxf(e, 0.f) + 0.2f * fminf(e, 0.f));
      e = elv + er1.x; av[4] = ad1.x * exp2f(fmaxf(e, 0.f) + 0.2f * fminf(e, 0.f));
      e = elv + er1.y; av[5] = ad1.y * exp2f(fmaxf(e, 0.f) + 0.2f * fminf(e, 0.f));
      e = elv + er1.z; av[6] = ad1.z * exp2f(fmaxf(e, 0.f) + 0.2f * fminf(e, 0.f));
      e = elv + er1.w; av[7] = ad1.w * exp2f(fmaxf(e, 0.f) + 0.2f * fminf(e, 0.f));
    }
    Sp += ((av[0] + av[1]) + (av[2] + av[3])) + ((av[4] + av[5]) + (av[6] + av[7]));
    u16x8 pk;
    #pragma unroll
    for (int q = 0; q < 8; ++q) pk[q] = f2bf(av[q]);
    *(u16x8*)(Ab + a_waddr) = pk;
    // ---- stage B (hT tile) ----
    const u16* hsrc = hT + (size_t)bd * NN + jb + bk0;
    const u16x8 hv0 = *(const u16x8*)hsrc;
    const u16x8 hv1 = *(const u16x8*)(hsrc + (size_t)64 * NN);
    *(u16x8*)(Bb + b_waddr0) = hv0;
    *(u16x8*)(Bb + b_waddr1) = hv1;
    __syncthreads();
    // ---- MFMA: 2 k-steps x 4 col-tiles ----
    #pragma unroll
    for (int kk = 0; kk < 2; ++kk) {
      const unsigned kbyte = (unsigned)(kk * 64 + lhi * 16);
      const bf16x8 af = *(const bf16x8*)(Ab + (am * 128 + (kbyte ^ aswz)));
      #pragma unroll
      for (int ct = 0; ct < 4; ++ct) {
        const int col = ch * 64 + ct * 16 + l15;
        const bf16x8 bfr = *(const bf16x8*)(Bb + (col * 128 + (kbyte ^ (unsigned)((col & 7) << 4))));
        acc[ct] = __builtin_amdgcn_mfma_f32_16x16x32_bf16(af, bfr, acc[ct], 0, 0, 0);
      }
    }
  }
  // ---- row-sum reduction (8 consecutive lanes per m' row) ----
  Sp += __shfl_xor(Sp, 1);
  Sp += __shfl_xor(Sp, 2);
  Sp += __shfl_xor(Sp, 4);
  if ((t & 7) == 0) S_lds[row] = Sp;
  __syncthreads();
  // ---- epilogue: normalize + bias + store ----
  #pragma unroll
  for (int reg = 0; reg < 4; ++reg) {
    const int mrow = rt * 16 + lhi * 4 + reg;   // C/D layout: row=(lane>>4)*4+reg
    const float S = S_lds[mrow];
    const float inv = 1.f / fmaxf(S, 1e-12f);
    const int irow = i0 + (mrow & 15);
    #pragma unroll
    for (int ct = 0; ct < 4; ++ct) {
      const int colp = ch * 64 + ct * 16 + l15; // C/D layout: col=lane&15
      out[(size_t)irow * (NH * DOUT) + rt * DOUT + colp] = acc[ct][reg] * inv + bias[colp];
    }
  }
}

extern "C" void kernel_launch(void* const* d_in, const int* in_sizes, int n_in,
                              void* d_out, int out_size, void* d_ws, size_t ws_size,
                              hipStream_t stream) {
  const float* adj = (const float*)d_in[0];
  const float* x   = (const float*)d_in[1];
  const float* W   = (const float*)d_in[2];
  const float* alw = (const float*)d_in[3];
  const float* arw = (const float*)d_in[4];
  const float* bias= (const float*)d_in[5];
  float* out = (float*)d_out;
  char* ws = (char*)d_ws;
  u16*   hT  = (u16*)ws;                               // 128*4096*2 = 1 MB
  float* el  = (float*)(ws + (1 << 20));               // 4096*4*4 = 64 KB
  float* erT = (float*)(ws + (1 << 20) + (64 << 10));  // 4*4096*4 = 64 KB
  precompute_kernel<<<256, 512, 0, stream>>>(x, W, alw, arw, hT, el, erT);
  gat_main<<<256, 512, 0, stream>>>(adj, hT, el, erT, bias, out);
}

// Round 2
// 177.284 us; speedup vs baseline: 1.1139x; 1.1139x over previous
//
#include <hip/hip_runtime.h>

#define NN 4096
#define DIN 512
#define DOUT 128
#define NH 4
#define LOG2E 1.44269504088896340736f

typedef __bf16 bf16x8 __attribute__((ext_vector_type(8)));
typedef float f32x4 __attribute__((ext_vector_type(4)));
typedef unsigned short u16;
typedef u16 u16x8 __attribute__((ext_vector_type(8)));
typedef unsigned long long u64;

static __device__ __forceinline__ u16 f2bf(float f) {
  __bf16 h = (__bf16)f;
  return __builtin_bit_cast(u16, h);
}

// ---------------- Kernel 0: pack adj (0/1 fp32) into bitmask ----------------
// adjW[i*64 + jw] bit n = (adj[i][jw*64+n] != 0)
__global__ __launch_bounds__(256) void pack_adj(const float* __restrict__ adj,
                                                u64* __restrict__ adjW) {
  const int t = threadIdx.x;
  const int lane = t & 63;
  const int wv = t >> 6;
  const size_t blk = blockIdx.x;
  #pragma unroll
  for (int it = 0; it < 4; ++it) {
    const size_t wbase = blk * 128 + it * 32 + wv * 8;
    float v[8];
    #pragma unroll
    for (int u = 0; u < 8; ++u) v[u] = adj[(wbase + u) * 64 + lane];
    #pragma unroll
    for (int u = 0; u < 8; ++u) {
      const u64 m = __ballot(v[u] != 0.0f);
      if (lane == 0) adjW[wbase + u] = m;
    }
  }
}

// ---------------- Kernel 1: transpose + hi/lo split of W --------------------
// W [512k][128n] fp32 -> wthi/wtlo [128n][512k] bf16
__global__ __launch_bounds__(256) void prep_wt(const float* __restrict__ W,
                                               u16* __restrict__ wthi,
                                               u16* __restrict__ wtlo) {
  const int n = blockIdx.x;
  const int t = threadIdx.x;
  for (int k = t; k < 512; k += 256) {
    const float w = W[(size_t)k * 128 + n];
    const __bf16 hi = (__bf16)w;
    const float lo = w - (float)hi;
    wthi[(size_t)n * 512 + k] = __builtin_bit_cast(u16, hi);
    wtlo[(size_t)n * 512 + k] = f2bf(lo);
  }
}

// ---------------- Kernel 2: h = x@W (split-bf16 MFMA), hT/el/erT ------------
// grid 256 x 256 thr (4 waves). Block: 16 rows x 128 cols, K=512 in 4 chunks.
__global__ __launch_bounds__(256, 2) void hcompute(
    const float* __restrict__ x, const u16* __restrict__ wthi,
    const u16* __restrict__ wtlo, const float* __restrict__ alw,
    const float* __restrict__ arw, u16* __restrict__ hT,
    float* __restrict__ el, float* __restrict__ erT) {
  __shared__ __align__(16) char pool[73728];
  // xh [16][128] bf16 swz @0 (4KB); xl @4096; wh [128][128] bf16 swz @8192
  // (32KB); wl @40960 (32KB); h_lds [16][132] f32 aliases @8192 after MFMA.
  float* h_lds = (float*)(pool + 8192);
  const int t = threadIdx.x;
  const int i0 = blockIdx.x * 16;
  const int lane = t & 63, wv = t >> 6;
  const int l15 = lane & 15, lhi = lane >> 4;
  f32x4 acc[2];
  #pragma unroll
  for (int nt = 0; nt < 2; ++nt) acc[nt] = (f32x4){0.f, 0.f, 0.f, 0.f};
  const int xr = t >> 4, xq = (t & 15) * 8;
  const unsigned x_waddr = (unsigned)(xr * 256 + xq * 2) ^ (unsigned)((xr & 7) << 4);
  const int wn = t >> 1, wkh = (t & 1) * 64;

  for (int kc = 0; kc < 4; ++kc) {
    __syncthreads();
    // stage x tile (hi/lo)
    {
      const float* xsrc = x + (size_t)(i0 + xr) * DIN + kc * 128 + xq;
      float xv[8];
      *(float4*)xv = *(const float4*)xsrc;
      *(float4*)(xv + 4) = *(const float4*)(xsrc + 4);
      u16x8 xhi, xlo;
      #pragma unroll
      for (int q = 0; q < 8; ++q) {
        const __bf16 hh = (__bf16)xv[q];
        xhi[q] = __builtin_bit_cast(u16, hh);
        xlo[q] = f2bf(xv[q] - (float)hh);
      }
      *(u16x8*)(pool + x_waddr) = xhi;
      *(u16x8*)(pool + 4096 + x_waddr) = xlo;
    }
    // stage W^T tiles (hi/lo)
    {
      const u16* whsrc = wthi + (size_t)wn * 512 + kc * 128 + wkh;
      const u16* wlsrc = wtlo + (size_t)wn * 512 + kc * 128 + wkh;
      #pragma unroll
      for (int q = 0; q < 8; ++q) {
        const unsigned addr =
            (unsigned)(wn * 256 + (wkh + q * 8) * 2) ^ (unsigned)((wn & 7) << 4);
        *(u16x8*)(pool + 8192 + addr) = *(const u16x8*)(whsrc + q * 8);
        *(u16x8*)(pool + 40960 + addr) = *(const u16x8*)(wlsrc + q * 8);
      }
    }
    __syncthreads();
    // MFMA: 4 k-steps x 2 n-tiles x 3 terms
    #pragma unroll
    for (int ks = 0; ks < 4; ++ks) {
      const unsigned kbyte = (unsigned)(ks * 64 + lhi * 16);
      const unsigned xoff = (unsigned)(l15 * 256) + (kbyte ^ (unsigned)((l15 & 7) << 4));
      const bf16x8 ah = *(const bf16x8*)(pool + xoff);
      const bf16x8 al = *(const bf16x8*)(pool + 4096 + xoff);
      #pragma unroll
      for (int nt = 0; nt < 2; ++nt) {
        const int n = wv * 32 + nt * 16 + l15;
        const unsigned wb = (unsigned)(n * 256) + (kbyte ^ (unsigned)((n & 7) << 4));
        const bf16x8 bh = *(const bf16x8*)(pool + 8192 + wb);
        const bf16x8 bl = *(const bf16x8*)(pool + 40960 + wb);
        acc[nt] = __builtin_amdgcn_mfma_f32_16x16x32_bf16(ah, bh, acc[nt], 0, 0, 0);
        acc[nt] = __builtin_amdgcn_mfma_f32_16x16x32_bf16(al, bh, acc[nt], 0, 0, 0);
        acc[nt] = __builtin_amdgcn_mfma_f32_16x16x32_bf16(ah, bl, acc[nt], 0, 0, 0);
      }
    }
  }
  __syncthreads();  // all MFMA reads of wh done before h_lds overwrites it
  #pragma unroll
  for (int nt = 0; nt < 2; ++nt)
    #pragma unroll
    for (int reg = 0; reg < 4; ++reg)
      h_lds[(lhi * 4 + reg) * 132 + wv * 32 + nt * 16 + l15] = acc[nt][reg];
  __syncthreads();
  // hT store (bf16, [d][i])
  {
    const int d = t >> 1, ih = (t & 1) * 8;
    u16x8 hv;
    #pragma unroll
    for (int q = 0; q < 8; ++q) hv[q] = f2bf(h_lds[(ih + q) * 132 + d]);
    *(u16x8*)(hT + (size_t)d * NN + i0 + ih) = hv;
  }
  // el/erT (fp32 dots, pre-scaled by log2e)
  if (t < 128) {
    const int r = t >> 3, hh = (t >> 1) & 3, side = t & 1;
    const float* wrow = (side ? arw : alw) + hh * DOUT;
    float s = 0.f;
    for (int d = 0; d < 128; ++d) s += h_lds[r * 132 + d] * wrow[d];
    s *= LOG2E;
    if (side == 0) el[(size_t)(i0 + r) * NH + hh] = s;
    else erT[(size_t)hh * NN + i0 + r] = s;
  }
}

// ---------------- Kernel 3: fused weight-gen + PV GEMM ----------------------
// Block: 16 graph rows x 4 heads = 64 MFMA rows x 128 cols; K-loop over j.
// KSPLIT blocks share each row group; partials to ws (KSPLIT=2).
template <int KSPLIT>
__global__ __launch_bounds__(512, 4) void gat_main(
    const unsigned char* __restrict__ adjB, const u16* __restrict__ hT,
    const float* __restrict__ el, const float* __restrict__ erT,
    const float* __restrict__ bias, float* __restrict__ outp,
    float* __restrict__ accP, float* __restrict__ SP) {
  constexpr int NIT = 64 / KSPLIT;
  __shared__ __align__(16) u16 A_lds[2][64 * 64];
  __shared__ __align__(16) u16 B_lds[2][128 * 64];
  __shared__ float S_lds[64];
  const int t = threadIdx.x;
  const int b = blockIdx.x;
  const int g = b & 255;
  const int ks = (KSPLIT > 1) ? (b >> 8) : 0;
  const int i0 = g * 16;
  // A-gen mapping
  const int row = t >> 3, head = row >> 4, il = row & 15;
  const int j0 = (t & 7) * 8;
  const float elv = el[(size_t)(i0 + il) * NH + head];
  const unsigned char* adjrow =
      adjB + (size_t)(i0 + il) * 512 + (size_t)ks * NIT * 8 + (t & 7);
  const float* errow = erT + (size_t)head * NN + ks * NIT * 64 + j0;
  const unsigned a_off = (unsigned)(row * 128 + j0 * 2) ^ (unsigned)((row & 7) << 4);
  // B staging mapping
  const int bd = t >> 3, bk0 = (t & 7) * 8;
  const u16* hrow = hT + (size_t)bd * NN + ks * NIT * 64 + bk0;
  const unsigned b_off0 = (unsigned)(bd * 128 + bk0 * 2) ^ (unsigned)((bd & 7) << 4);
  const unsigned b_off1 =
      (unsigned)((bd + 64) * 128 + bk0 * 2) ^ (unsigned)((bd & 7) << 4);
  // MFMA mapping
  const int lane = t & 63, w = t >> 6;
  const int rt = w >> 1, ch = w & 1;
  const int l15 = lane & 15, lhi = lane >> 4;
  const int am = rt * 16 + l15;
  const unsigned aswz = (unsigned)((am & 7) << 4);
  f32x4 acc[4];
  #pragma unroll
  for (int ct = 0; ct < 4; ++ct) acc[ct] = (f32x4){0.f, 0.f, 0.f, 0.f};
  float Sp = 0.f;

  auto genTile = [&](unsigned char abv, const float4& ea, const float4& eb,
                     char* Abuf, char* Bbuf, const u16x8& h0, const u16x8& h1) {
    float ev[8];
    *(float4*)ev = ea;
    *(float4*)(ev + 4) = eb;
    u16x8 pk;
    float s = 0.f;
    #pragma unroll
    for (int q = 0; q < 8; ++q) {
      const float e = elv + ev[q];
      const float ex = exp2f(fmaxf(e, 0.f) + 0.2f * fminf(e, 0.f));
      const float av = (float)((abv >> q) & 1) * ex;
      s += av;
      pk[q] = f2bf(av);
    }
    Sp += s;
    *(u16x8*)(Abuf + a_off) = pk;
    *(u16x8*)(Bbuf + b_off0) = h0;
    *(u16x8*)(Bbuf + b_off1) = h1;
  };

  // prologue: tile 0
  {
    const unsigned char ab = adjrow[0];
    const float4 e0 = *(const float4*)errow;
    const float4 e1 = *(const float4*)(errow + 4);
    const u16x8 h0 = *(const u16x8*)hrow;
    const u16x8 h1 = *(const u16x8*)(hrow + (size_t)64 * NN);
    genTile(ab, e0, e1, (char*)A_lds[0], (char*)B_lds[0], h0, h1);
  }

  for (int jt = 0; jt < NIT; ++jt) {
    const int cur = jt & 1;
    __syncthreads();
    // prefetch inputs for jt+1 (issued before MFMAs; consumed after)
    unsigned char abn = 0;
    float4 e0n, e1n;
    u16x8 h0n, h1n;
    const bool more = (jt + 1 < NIT);
    if (more) {
      abn = adjrow[(jt + 1) * 8];
      e0n = *(const float4*)(errow + (jt + 1) * 64);
      e1n = *(const float4*)(errow + (jt + 1) * 64 + 4);
      h0n = *(const u16x8*)(hrow + (jt + 1) * 64);
      h1n = *(const u16x8*)(hrow + (jt + 1) * 64 + (size_t)64 * NN);
    }
    // MFMA on buf[cur]
    const char* Abc = (const char*)A_lds[cur];
    const char* Bbc = (const char*)B_lds[cur];
    #pragma unroll
    for (int kk = 0; kk < 2; ++kk) {
      const unsigned kbyte = (unsigned)(kk * 64 + lhi * 16);
      const bf16x8 af = *(const bf16x8*)(Abc + (am * 128 + (kbyte ^ aswz)));
      #pragma unroll
      for (int ct = 0; ct < 4; ++ct) {
        const int col = ch * 64 + ct * 16 + l15;
        const bf16x8 bfr = *(const bf16x8*)(
            Bbc + (col * 128 + (kbyte ^ (unsigned)((col & 7) << 4))));
        acc[ct] = __builtin_amdgcn_mfma_f32_16x16x32_bf16(af, bfr, acc[ct], 0, 0, 0);
      }
    }
    // generate tile jt+1 into the other buffer
    if (more)
      genTile(abn, e0n, e1n, (char*)A_lds[cur ^ 1], (char*)B_lds[cur ^ 1], h0n, h1n);
  }

  // row-sum reduce across the 8 j-lanes of each row
  Sp += __shfl_xor(Sp, 1);
  Sp += __shfl_xor(Sp, 2);
  Sp += __shfl_xor(Sp, 4);

  if (KSPLIT == 1) {
    if ((t & 7) == 0) S_lds[row] = Sp;
    __syncthreads();
    #pragma unroll
    for (int reg = 0; reg < 4; ++reg) {
      const int mrow = rt * 16 + lhi * 4 + reg;
      const float inv = 1.f / fmaxf(S_lds[mrow], 1e-12f);
      const int irow = i0 + (mrow & 15);
      #pragma unroll
      for (int ct = 0; ct < 4; ++ct) {
        const int colp = ch * 64 + ct * 16 + l15;
        outp[(size_t)irow * (NH * DOUT) + rt * DOUT + colp] =
            acc[ct][reg] * inv + bias[colp];
      }
    }
  } else {
    if ((t & 7) == 0) SP[(size_t)b * 64 + row] = Sp;
    float* dst = accP + (size_t)b * 8192;
    #pragma unroll
    for (int reg = 0; reg < 4; ++reg) {
      const int mrow = rt * 16 + lhi * 4 + reg;
      #pragma unroll
      for (int ct = 0; ct < 4; ++ct) {
        const int colp = ch * 64 + ct * 16 + l15;
        dst[mrow * 128 + colp] = acc[ct][reg];
      }
    }
  }
}

// ---------------- Kernel 4: reduce partials + normalize + bias --------------
__global__ __launch_bounds__(256) void reduce_norm(
    const float* __restrict__ accP, const float* __restrict__ SP,
    const float* __restrict__ bias, float* __restrict__ outp) {
  const int idx = blockIdx.x * 256 + threadIdx.x;
  const int o = idx * 4;
  const int d = o & 127;
  const int h = (o >> 7) & 3;
  const int i = o >> 9;
  const int g = i >> 4;
  const int m = h * 16 + (i & 15);
  const float4 p0 = *(const float4*)(accP + (size_t)g * 8192 + m * 128 + d);
  const float4 p1 = *(const float4*)(accP + (size_t)(256 + g) * 8192 + m * 128 + d);
  const float S = SP[(size_t)g * 64 + m] + SP[(size_t)(256 + g) * 64 + m];
  const float inv = 1.f / fmaxf(S, 1e-12f);
  const float4 bb = *(const float4*)(bias + d);
  float4 r;
  r.x = (p0.x + p1.x) * inv + bb.x;
  r.y = (p0.y + p1.y) * inv + bb.y;
  r.z = (p0.z + p1.z) * inv + bb.z;
  r.w = (p0.w + p1.w) * inv + bb.w;
  *(float4*)(outp + o) = r;
}

extern "C" void kernel_launch(void* const* d_in, const int* in_sizes, int n_in,
                              void* d_out, int out_size, void* d_ws, size_t ws_size,
                              hipStream_t stream) {
  const float* adj = (const float*)d_in[0];
  const float* x = (const float*)d_in[1];
  const float* W = (const float*)d_in[2];
  const float* alw = (const float*)d_in[3];
  const float* arw = (const float*)d_in[4];
  const float* bias = (const float*)d_in[5];
  float* out = (float*)d_out;
  char* ws = (char*)d_ws;
  // ws layout
  u16* hT = (u16*)ws;                              // 1 MB
  float* el = (float*)(ws + 0x100000);             // 64 KB
  float* erT = (float*)(ws + 0x110000);            // 64 KB
  unsigned char* adjB = (unsigned char*)(ws + 0x120000);  // 2 MB
  u16* wthi = (u16*)(ws + 0x320000);               // 128 KB
  u16* wtlo = (u16*)(ws + 0x340000);               // 128 KB
  float* accP = (float*)(ws + 0x360000);           // 16 MB
  float* SP = (float*)(ws + 0x1360000);            // 128 KB
  const bool ksplit2 = ws_size >= 0x1380000ull;

  pack_adj<<<2048, 256, 0, stream>>>(adj, (u64*)adjB);
  prep_wt<<<128, 256, 0, stream>>>(W, wthi, wtlo);
  hcompute<<<256, 256, 0, stream>>>(x, wthi, wtlo, alw, arw, hT, el, erT);
  if (ksplit2) {
    gat_main<2><<<512, 512, 0, stream>>>(adjB, hT, el, erT, bias, out, accP, SP);
    reduce_norm<<<2048, 256, 0, stream>>>(accP, SP, bias, out);
  } else {
    gat_main<1><<<256, 512, 0, stream>>>(adjB, hT, el, erT, bias, out, accP, SP);
  }
}

// Round 3
// 170.285 us; speedup vs baseline: 1.1597x; 1.0411x over previous
//
#include <hip/hip_runtime.h>

#define NN 4096
#define DIN 512
#define DOUT 128
#define NH 4
#define LOG2E 1.44269504088896340736f

typedef __bf16 bf16x8 __attribute__((ext_vector_type(8)));
typedef float f32x4 __attribute__((ext_vector_type(4)));
typedef unsigned short u16;
typedef u16 u16x8 __attribute__((ext_vector_type(8)));
typedef u16 u16x4 __attribute__((ext_vector_type(4)));
typedef unsigned long long u64;

static __device__ __forceinline__ u16 f2bf(float f) {
  __bf16 h = (__bf16)f;
  return __builtin_bit_cast(u16, h);
}

// async global->LDS, 16B per lane; dest must be wave-uniform base + lane*16
static __device__ __forceinline__ void gl_lds16(const void* g, void* l) {
  __builtin_amdgcn_global_load_lds(
      (const __attribute__((address_space(1))) unsigned int*)g,
      (__attribute__((address_space(3))) unsigned int*)l, 16, 0, 0);
}

// ---------------- Kernel 0: pack adj (0/1 fp32) into bitmask ----------------
__global__ __launch_bounds__(256) void pack_adj(const float* __restrict__ adj,
                                                u64* __restrict__ adjW) {
  const int t = threadIdx.x;
  const int lane = t & 63;
  const int wv = t >> 6;
  const size_t blk = blockIdx.x;
  #pragma unroll
  for (int it = 0; it < 4; ++it) {
    const size_t wbase = blk * 128 + it * 32 + wv * 8;
    float v[8];
    #pragma unroll
    for (int u = 0; u < 8; ++u) v[u] = adj[(wbase + u) * 64 + lane];
    #pragma unroll
    for (int u = 0; u < 8; ++u) {
      const u64 m = __ballot(v[u] != 0.0f);
      if (lane == 0) adjW[wbase + u] = m;
    }
  }
}

// ---------------- Kernel 1: transpose + hi/lo split of W --------------------
__global__ __launch_bounds__(256) void prep_wt(const float* __restrict__ W,
                                               u16* __restrict__ wthi,
                                               u16* __restrict__ wtlo) {
  const int n = blockIdx.x;
  const int t = threadIdx.x;
  for (int k = t; k < 512; k += 256) {
    const float w = W[(size_t)k * 128 + n];
    const __bf16 hi = (__bf16)w;
    const float lo = w - (float)hi;
    wthi[(size_t)n * 512 + k] = __builtin_bit_cast(u16, hi);
    wtlo[(size_t)n * 512 + k] = f2bf(lo);
  }
}

// ---------------- Kernel 2: h = x@W (split-bf16 MFMA), hT/el/erT ------------
// 512 thr (8 waves, wave w -> cols w*16..+15), K=512 in 4 chunks, dbuf LDS.
__global__ __launch_bounds__(512, 1) void hcompute(
    const float* __restrict__ x, const u16* __restrict__ wthi,
    const u16* __restrict__ wtlo, const float* __restrict__ alw,
    const float* __restrict__ arw, u16* __restrict__ hT,
    float* __restrict__ el, float* __restrict__ erT) {
  // xh[2]@0 (4KB each), xl[2]@8192, wh[2]@16384 (32KB each), wl[2]@81920
  __shared__ __align__(16) char pool[147456];
  const int t = threadIdx.x;
  const int i0 = blockIdx.x * 16;
  const int lane = t & 63, w = t >> 6;
  const int l15 = lane & 15, lhi = lane >> 4;

  const int xr = t >> 5, xk = (t & 31) * 4;
  const unsigned x_off =
      ((unsigned)(xr * 256 + xk * 2)) ^ ((unsigned)((xr & 7) << 4));

  f32x4 acc = (f32x4){0.f, 0.f, 0.f, 0.f};

  // W stage via gload_lds: linear dest, pre-swizzled source
  auto stageW = [&](int kc, int buf) {
    #pragma unroll
    for (int q = 0; q < 4; ++q) {
      const int off = q * 8192 + t * 16;
      const int n = off >> 8;
      const int kb = off & 255;
      const int ksrc = (kb ^ ((n & 7) << 4)) >> 1;
      const size_t so = (size_t)n * 512 + kc * 128 + ksrc;
      gl_lds16(wthi + so, pool + 16384 + buf * 32768 + off);
      gl_lds16(wtlo + so, pool + 81920 + buf * 32768 + off);
    }
  };
  auto writeX = [&](const float4& xv, int buf) {
    u16x4 hi, lo;
    const float* xp = (const float*)&xv;
    #pragma unroll
    for (int j = 0; j < 4; ++j) {
      const __bf16 hb = (__bf16)xp[j];
      hi[j] = __builtin_bit_cast(u16, hb);
      lo[j] = f2bf(xp[j] - (float)hb);
    }
    *(u16x4*)(pool + buf * 4096 + x_off) = hi;
    *(u16x4*)(pool + 8192 + buf * 4096 + x_off) = lo;
  };

  // prologue
  stageW(0, 0);
  {
    float4 xv = *(const float4*)(x + (size_t)(i0 + xr) * DIN + xk);
    writeX(xv, 0);
  }
  float4 xnext;
  for (int kc = 0; kc < 4; ++kc) {
    const int cur = kc & 1;
    __syncthreads();  // drains gload_lds + x writes for buf cur
    const bool more = (kc < 3);
    if (more) {
      stageW(kc + 1, cur ^ 1);
      xnext = *(const float4*)(x + (size_t)(i0 + xr) * DIN + (kc + 1) * 128 + xk);
    }
    #pragma unroll
    for (int ks = 0; ks < 4; ++ks) {
      const unsigned kbyte = (unsigned)(ks * 64 + lhi * 16);
      const unsigned xoff =
          (unsigned)(l15 * 256) + (kbyte ^ (unsigned)((l15 & 7) << 4));
      const bf16x8 ah = *(const bf16x8*)(pool + cur * 4096 + xoff);
      const bf16x8 al = *(const bf16x8*)(pool + 8192 + cur * 4096 + xoff);
      const int n = w * 16 + l15;
      const unsigned wb =
          (unsigned)(n * 256) + (kbyte ^ (unsigned)((n & 7) << 4));
      const bf16x8 bh = *(const bf16x8*)(pool + 16384 + cur * 32768 + wb);
      const bf16x8 bl = *(const bf16x8*)(pool + 81920 + cur * 32768 + wb);
      acc = __builtin_amdgcn_mfma_f32_16x16x32_bf16(ah, bh, acc, 0, 0, 0);
      acc = __builtin_amdgcn_mfma_f32_16x16x32_bf16(al, bh, acc, 0, 0, 0);
      acc = __builtin_amdgcn_mfma_f32_16x16x32_bf16(ah, bl, acc, 0, 0, 0);
    }
    if (more) writeX(xnext, cur ^ 1);
  }
  __syncthreads();
  float* h_lds = (float*)(pool + 16384);  // [16][132]
  #pragma unroll
  for (int reg = 0; reg < 4; ++reg)
    h_lds[(lhi * 4 + reg) * 132 + w * 16 + l15] = acc[reg];
  __syncthreads();
  // hT store (bf16, [d][i])
  {
    const int d = t >> 2, ih0 = (t & 3) * 4;
    u16x4 hv;
    #pragma unroll
    for (int j = 0; j < 4; ++j) hv[j] = f2bf(h_lds[(ih0 + j) * 132 + d]);
    *(u16x4*)(hT + (size_t)d * NN + i0 + ih0) = hv;
  }
  // el/erT (fp32 dots, pre-scaled by log2e)
  if (t < 128) {
    const int r = t >> 3, hh = (t >> 1) & 3, side = t & 1;
    const float* wrow = (side ? arw : alw) + hh * DOUT;
    float s = 0.f;
    for (int d = 0; d < 128; ++d) s += h_lds[r * 132 + d] * wrow[d];
    s *= LOG2E;
    if (side == 0) el[(size_t)(i0 + r) * NH + hh] = s;
    else erT[(size_t)hh * NN + i0 + r] = s;
  }
}

// ---------------- Kernel 3: fused weight-gen + PV GEMM ----------------------
template <int KSPLIT>
__global__ __launch_bounds__(512, 4) void gat_main(
    const unsigned char* __restrict__ adjB, const u16* __restrict__ hT,
    const float* __restrict__ el, const float* __restrict__ erT,
    const float* __restrict__ bias, float* __restrict__ outp,
    float* __restrict__ accP, float* __restrict__ SP) {
  __shared__ __align__(16) u16 A_lds[2][64 * 64];
  __shared__ __align__(16) u16 B_lds[2][128 * 64];
  __shared__ float S_lds[64];
  const int t = threadIdx.x;
  const int b = blockIdx.x;
  const int g = b & 255;
  const int ks = (KSPLIT > 1) ? (b >> 8) : 0;
  const int i0 = g * 16;
  const int jbeg = (ks * 64) / KSPLIT;
  const int jcnt = ((ks + 1) * 64) / KSPLIT - jbeg;
  // A-gen mapping: thread -> (m' row, 8 consecutive j)
  const int row = t >> 3, head = row >> 4, il = row & 15;
  const float elv = el[(size_t)(i0 + il) * NH + head];
  const unsigned char* adjrow = adjB + (size_t)(i0 + il) * 512 + jbeg * 8 + (t & 7);
  const float* errow = erT + (size_t)head * NN + jbeg * 64 + (t & 7) * 8;
  const unsigned a_off =
      (unsigned)(row * 128 + (t & 7) * 16) ^ (unsigned)((row & 7) << 4);
  // B gload mapping: linear dest t*16 -> (row bd, byte col bkb), preswz source
  const int bd = t >> 3;
  const int bkb = (t & 7) * 16;
  const u16* hsrc = hT + (size_t)bd * NN + jbeg * 64 +
                    (((unsigned)bkb ^ (unsigned)((bd & 7) << 4)) >> 1);
  // MFMA mapping
  const int lane = t & 63, w = t >> 6;
  const int rt = w >> 1, ch = w & 1;
  const int l15 = lane & 15, lhi = lane >> 4;
  const int am = rt * 16 + l15;
  const unsigned aswz = (unsigned)((am & 7) << 4);
  f32x4 acc[4];
  #pragma unroll
  for (int ct = 0; ct < 4; ++ct) acc[ct] = (f32x4){0.f, 0.f, 0.f, 0.f};
  float Sp = 0.f;

  auto stageB = [&](int jt, int buf) {
    char* dst = (char*)B_lds[buf] + t * 16;
    gl_lds16(hsrc + jt * 64, dst);
    gl_lds16(hsrc + jt * 64 + (size_t)64 * NN, dst + 8192);
  };
  auto genA = [&](unsigned char abv, const float4& ea, const float4& eb, int buf) {
    float ev[8];
    *(float4*)ev = ea;
    *(float4*)(ev + 4) = eb;
    u16x8 pk;
    float s = 0.f;
    #pragma unroll
    for (int q = 0; q < 8; ++q) {
      const float e = elv + ev[q];
      const float l = fmaf(0.4f, __builtin_fabsf(e), 0.6f * e);  // lrelu (exact)
      const float ex = exp2f(l);
      const int msk = ((int)((unsigned)abv << (31 - q))) >> 31;  // bit->0/-1
      const float av = __builtin_bit_cast(float, __builtin_bit_cast(int, ex) & msk);
      s += av;
      pk[q] = f2bf(av);
    }
    Sp += s;
    *(u16x8*)((char*)A_lds[buf] + a_off) = pk;
  };

  // prologue: tile 0
  stageB(0, 0);
  {
    const unsigned char ab = adjrow[0];
    const float4 e0 = *(const float4*)errow;
    const float4 e1 = *(const float4*)(errow + 4);
    genA(ab, e0, e1, 0);
  }

  for (int jt = 0; jt < jcnt; ++jt) {
    const int cur = jt & 1;
    __syncthreads();  // drains B gloads + A writes of buf cur; prev reads done
    const bool more = (jt + 1 < jcnt);
    unsigned char abn = 0;
    float4 e0n = {0, 0, 0, 0}, e1n = {0, 0, 0, 0};
    if (more) {
      stageB(jt + 1, cur ^ 1);  // async, drains at next barrier
      abn = adjrow[(jt + 1) * 8];
      e0n = *(const float4*)(errow + (jt + 1) * 64);
      e1n = *(const float4*)(errow + (jt + 1) * 64 + 4);
    }
    const char* Abc = (const char*)A_lds[cur];
    const char* Bbc = (const char*)B_lds[cur];
    #pragma unroll
    for (int kk = 0; kk < 2; ++kk) {
      const unsigned kbyte = (unsigned)(kk * 64 + lhi * 16);
      const bf16x8 af = *(const bf16x8*)(Abc + (am * 128 + (kbyte ^ aswz)));
      #pragma unroll
      for (int ct = 0; ct < 4; ++ct) {
        const int col = ch * 64 + ct * 16 + l15;
        const bf16x8 bfr = *(const bf16x8*)(
            Bbc + (col * 128 + (kbyte ^ (unsigned)((col & 7) << 4))));
        acc[ct] = __builtin_amdgcn_mfma_f32_16x16x32_bf16(af, bfr, acc[ct], 0, 0, 0);
      }
    }
    if (more) genA(abn, e0n, e1n, cur ^ 1);
  }

  // row-sum reduce across the 8 j-lanes of each row
  Sp += __shfl_xor(Sp, 1);
  Sp += __shfl_xor(Sp, 2);
  Sp += __shfl_xor(Sp, 4);

  if (KSPLIT == 1) {
    if ((t & 7) == 0) S_lds[row] = Sp;
    __syncthreads();
    #pragma unroll
    for (int reg = 0; reg < 4; ++reg) {
      const int mrow = rt * 16 + lhi * 4 + reg;
      const float inv = 1.f / fmaxf(S_lds[mrow], 1e-12f);
      const int irow = i0 + (mrow & 15);
      #pragma unroll
      for (int ct = 0; ct < 4; ++ct) {
        const int colp = ch * 64 + ct * 16 + l15;
        outp[(size_t)irow * (NH * DOUT) + rt * DOUT + colp] =
            acc[ct][reg] * inv + bias[colp];
      }
    }
  } else {
    if ((t & 7) == 0) SP[(size_t)b * 64 + row] = Sp;
    float* dst = accP + (size_t)b * 8192;
    #pragma unroll
    for (int reg = 0; reg < 4; ++reg) {
      const int mrow = rt * 16 + lhi * 4 + reg;
      #pragma unroll
      for (int ct = 0; ct < 4; ++ct) {
        const int colp = ch * 64 + ct * 16 + l15;
        dst[mrow * 128 + colp] = acc[ct][reg];
      }
    }
  }
}

// ---------------- Kernel 4: reduce partials + normalize + bias --------------
template <int KS>
__global__ __launch_bounds__(256) void reduce_norm(
    const float* __restrict__ accP, const float* __restrict__ SP,
    const float* __restrict__ bias, float* __restrict__ outp) {
  const int idx = blockIdx.x * 256 + threadIdx.x;
  const int o = idx * 4;
  const int d = o & 127;
  const int hh = (o >> 7) & 3;
  const int i = o >> 9;
  const int g = i >> 4;
  const int m = hh * 16 + (i & 15);
  float4 p = make_float4(0.f, 0.f, 0.f, 0.f);
  float S = 0.f;
  #pragma unroll
  for (int s = 0; s < KS; ++s) {
    const float4 q =
        *(const float4*)(accP + (size_t)(s * 256 + g) * 8192 + m * 128 + d);
    p.x += q.x; p.y += q.y; p.z += q.z; p.w += q.w;
    S += SP[(size_t)(s * 256 + g) * 64 + m];
  }
  const float inv = 1.f / fmaxf(S, 1e-12f);
  const float4 bb = *(const float4*)(bias + d);
  float4 r;
  r.x = p.x * inv + bb.x;
  r.y = p.y * inv + bb.y;
  r.z = p.z * inv + bb.z;
  r.w = p.w * inv + bb.w;
  *(float4*)(outp + o) = r;
}

extern "C" void kernel_launch(void* const* d_in, const int* in_sizes, int n_in,
                              void* d_out, int out_size, void* d_ws, size_t ws_size,
                              hipStream_t stream) {
  const float* adj = (const float*)d_in[0];
  const float* x = (const float*)d_in[1];
  const float* W = (const float*)d_in[2];
  const float* alw = (const float*)d_in[3];
  const float* arw = (const float*)d_in[4];
  const float* bias = (const float*)d_in[5];
  float* out = (float*)d_out;
  char* ws = (char*)d_ws;
  u16* hT = (u16*)ws;                                     // 1 MB
  float* el = (float*)(ws + 0x100000);                    // 64 KB
  float* erT = (float*)(ws + 0x110000);                   // 64 KB
  unsigned char* adjB = (unsigned char*)(ws + 0x120000);  // 2 MB
  u16* wthi = (u16*)(ws + 0x320000);                      // 128 KB
  u16* wtlo = (u16*)(ws + 0x340000);                      // 128 KB
  float* accP = (float*)(ws + 0x360000);
  const size_t need3 = 0x360000ull + 768ull * 32768 + 768ull * 256;
  const size_t need2 = 0x360000ull + 512ull * 32768 + 512ull * 256;

  pack_adj<<<2048, 256, 0, stream>>>(adj, (u64*)adjB);
  prep_wt<<<128, 256, 0, stream>>>(W, wthi, wtlo);
  hcompute<<<256, 512, 0, stream>>>(x, wthi, wtlo, alw, arw, hT, el, erT);
  if (ws_size >= need3) {
    float* SP = (float*)(ws + 0x360000 + 768ull * 32768);
    gat_main<3><<<768, 512, 0, stream>>>(adjB, hT, el, erT, bias, out, accP, SP);
    reduce_norm<3><<<2048, 256, 0, stream>>>(accP, SP, bias, out);
  } else if (ws_size >= need2) {
    float* SP = (float*)(ws + 0x360000 + 512ull * 32768);
    gat_main<2><<<512, 512, 0, stream>>>(adjB, hT, el, erT, bias, out, accP, SP);
    reduce_norm<2><<<2048, 256, 0, stream>>>(accP, SP, bias, out);
  } else {
    gat_main<1><<<256, 512, 0, stream>>>(adjB, hT, el, erT, bias, out, accP, accP);
  }
}